// Round 5
// baseline (978.418 us; speedup 1.0000x reference)
//
#include <hip/hip_runtime.h>
#include <math.h>

// Problem dims
#define NB 128
#define NN 36
#define S36 37            // padded stride for 36x36 LDS arrays
#define NFEAT 2048
#define NMID 517
#define KP 544            // padded K (multiple of 32) for MID-dim GEMMs
#define NHID 128
#define NOUT 1024
#define ROWS (NB*NN)      // 4608

typedef __bf16 bf16x8 __attribute__((ext_vector_type(8)));
typedef float  f32x4  __attribute__((ext_vector_type(4)));

__device__ __forceinline__ float sigf(float x){ return 1.f/(1.f+expf(-x)); }
__device__ __forceinline__ unsigned short f2bf(float x){
    unsigned u = __float_as_uint(x);
    return (unsigned short)((u + 0x7FFFu + ((u>>16)&1u)) >> 16);
}
__device__ __forceinline__ float bf2f(unsigned short b){
    return __uint_as_float(((unsigned)b) << 16);
}

// ---------------------------------------------------------------------------
// per-batch box max + normalize, fill feats fp32 cols 0..4
// ---------------------------------------------------------------------------
__global__ __launch_bounds__(64) void fill_small(const float* __restrict__ boxes,
                                                 const float* __restrict__ att,
                                                 float* __restrict__ feats)
{
    int b = blockIdx.x, tid = threadIdx.x;
    float mx = -1e30f;
    for (int idx = tid; idx < 4*NN; idx += 64) mx = fmaxf(mx, boxes[b*4*NN + idx]);
    for (int off = 32; off > 0; off >>= 1) mx = fmaxf(mx, __shfl_down(mx, off));
    mx = __shfl(mx, 0);
    float inv = 1.f / mx;
    for (int idx = tid; idx < 4*NN; idx += 64) {
        int r = idx / NN, n = idx - r*NN;
        feats[(size_t)(b*NN+n)*NMID + r] = boxes[b*4*NN + idx] * inv;
    }
    if (tid < NN) feats[(size_t)(b*NN+tid)*NMID + 4] = att[b*NN + tid];
}

// ---------------------------------------------------------------------------
// cast / reorder prep kernels
// ---------------------------------------------------------------------------
__global__ __launch_bounds__(256) void cast_bf16(const float* __restrict__ s,
                                                 unsigned short* __restrict__ d, int n)
{
    int stride = gridDim.x*256;
    for (int i = blockIdx.x*256 + threadIdx.x; i < n; i += stride) d[i] = f2bf(s[i]);
}

__global__ __launch_bounds__(256) void cast_pad(const float* __restrict__ s,
                                                unsigned short* __restrict__ d,
                                                int rows, int sld)
{
    int n = rows*KP, stride = gridDim.x*256;
    for (int i = blockIdx.x*256 + threadIdx.x; i < n; i += stride) {
        int r = i / KP, k = i - r*KP;
        d[i] = (k < sld) ? f2bf(s[(size_t)r*sld + k]) : (unsigned short)0;
    }
}

__global__ __launch_bounds__(256) void build_wxy(const float* __restrict__ wx,
                                                 const float* __restrict__ wy,
                                                 const float* __restrict__ b1,
                                                 unsigned short* __restrict__ d,
                                                 float* __restrict__ hbias)
{
    int n = 256*KP, stride = gridDim.x*256;
    for (int i = blockIdx.x*256 + threadIdx.x; i < n; i += stride) {
        int r = i / KP, k = i - r*KP;
        float v = 0.f;
        if (k < NMID) v = (r < NHID) ? wx[(size_t)r*NMID+k] : wy[(size_t)(r-NHID)*NMID+k];
        d[i] = f2bf(v);
    }
    for (int i = blockIdx.x*256 + threadIdx.x; i < 256; i += stride)
        hbias[i] = (i < NHID) ? b1[i] : 0.f;
}

// w_ih (4096 x 517) -> interleaved row u*4+g, padded to KP, bf16
__global__ __launch_bounds__(256) void prep_wih(const float* __restrict__ w,
                                                unsigned short* __restrict__ d)
{
    int n = 4*NOUT*KP, stride = gridDim.x*256;
    for (int i = blockIdx.x*256 + threadIdx.x; i < n; i += stride) {
        int row = i / KP, k = i - row*KP;
        int u = row >> 2, g = row & 3;
        d[i] = (k < NMID) ? f2bf(w[(size_t)(g*NOUT+u)*NMID + k]) : (unsigned short)0;
    }
}

// w_hh (4096 x 1024) -> interleaved row u*4+g, bf16
__global__ __launch_bounds__(256) void prep_whh(const float* __restrict__ w,
                                                unsigned short* __restrict__ d)
{
    int n = 4*NOUT*NOUT, stride = gridDim.x*256;
    for (int i = blockIdx.x*256 + threadIdx.x; i < n; i += stride) {
        int row = i >> 10, k = i & 1023;
        int u = row >> 2, g = row & 3;
        d[i] = f2bf(w[(size_t)(g*NOUT+u)*NOUT + k]);
    }
}

__global__ __launch_bounds__(256) void prep_misc(const float* __restrict__ b_ih,
                                                 const float* __restrict__ b_hh,
                                                 float* __restrict__ comb,
                                                 unsigned short* __restrict__ h0,
                                                 float* __restrict__ c)
{
    int stride = gridDim.x*256;
    for (int i = blockIdx.x*256 + threadIdx.x; i < 4*NOUT; i += stride) {
        int u = i >> 2, g = i & 3;
        comb[i] = b_ih[g*NOUT+u] + b_hh[g*NOUT+u];
    }
    for (int i = blockIdx.x*256 + threadIdx.x; i < NB*NOUT; i += stride) {
        h0[i] = 0; c[i] = 0.f;
    }
}

// ---------------------------------------------------------------------------
// bf16 MFMA GEMM: C[m,n] = sum_k A[m,k]*B[n,k] + bias[n]
// Block tile 128x64, 256 thr = 4 waves (2x2), wave tile 64x32.
// ---------------------------------------------------------------------------
__global__ __launch_bounds__(256) void gemm_mfma(
    const unsigned short* __restrict__ A, const unsigned short* __restrict__ B,
    const float* __restrict__ bias, void* __restrict__ Cp,
    int K, int lda, int ldb, int ldc, int obf)
{
    __shared__ __align__(16) char As[8192];
    __shared__ __align__(16) char Bs[4096];
    int m0 = blockIdx.y * 128, n0 = blockIdx.x * 64;
    int tid = threadIdx.x;
    int lane = tid & 63, wave = tid >> 6;
    int wm = wave >> 1, wn = wave & 1;
    f32x4 acc[4][2];
    #pragma unroll
    for (int i = 0; i < 4; ++i)
        #pragma unroll
        for (int j = 0; j < 2; ++j) acc[i][j] = (f32x4){0.f,0.f,0.f,0.f};

    for (int k0 = 0; k0 < K; k0 += 32) {
        #pragma unroll
        for (int cc = tid; cc < 512; cc += 256) {
            int r = cc >> 2, q = cc & 3;
            uint4 v = *(const uint4*)(A + (size_t)(m0+r)*lda + k0 + q*8);
            *(uint4*)(As + ((r>>4)<<10) + (q<<8) + ((r&15)<<4)) = v;
        }
        {
            int r = tid >> 2, q = tid & 3;
            uint4 v = *(const uint4*)(B + (size_t)(n0+r)*ldb + k0 + q*8);
            *(uint4*)(Bs + ((r>>4)<<10) + (q<<8) + ((r&15)<<4)) = v;
        }
        __syncthreads();
        bf16x8 af[4], bfr[2];
        #pragma unroll
        for (int i = 0; i < 4; ++i) af[i]  = *(bf16x8*)(As + ((wm*4+i)<<10) + (lane<<4));
        #pragma unroll
        for (int j = 0; j < 2; ++j) bfr[j] = *(bf16x8*)(Bs + ((wn*2+j)<<10) + (lane<<4));
        #pragma unroll
        for (int i = 0; i < 4; ++i)
            #pragma unroll
            for (int j = 0; j < 2; ++j)
                acc[i][j] = __builtin_amdgcn_mfma_f32_16x16x32_bf16(af[i], bfr[j], acc[i][j], 0, 0, 0);
        __syncthreads();
    }
    int colf = lane & 15, rowq = lane >> 4;
    #pragma unroll
    for (int j = 0; j < 2; ++j) {
        int col = n0 + (wn*2+j)*16 + colf;
        float bv = bias ? bias[col] : 0.f;
        #pragma unroll
        for (int i = 0; i < 4; ++i) {
            #pragma unroll
            for (int reg = 0; reg < 4; ++reg) {
                int row = m0 + (wm*4+i)*16 + rowq*4 + reg;
                float v = acc[i][j][reg] + bv;
                if (obf) ((unsigned short*)Cp)[(size_t)row*ldc + col] = f2bf(v);
                else     ((float*)Cp)[(size_t)row*ldc + col] = v;
            }
        }
    }
}

// ---------------------------------------------------------------------------
// out_k: grid (128,4). Block (b,s) computes rows i0=s*9..s*9+8 of
// out[b][i][j] = sum_h w2[h]*relu(hx[i][h]+hy[j][h]) -> global f32.
// ---------------------------------------------------------------------------
__global__ __launch_bounds__(256) void out_k(
    const float* __restrict__ hxy, const float* __restrict__ w2,
    float* __restrict__ out_g)
{
    __shared__ float s_hx[9*129], s_hy[NN*129], s_w2[NHID];
    int b = blockIdx.x, i0 = blockIdx.y * 9, tid = threadIdx.x;
    for (int i = tid; i < 9*NHID; i += 256) {
        int n = i >> 7, h = i & 127;
        s_hx[n*129+h] = hxy[(size_t)(b*NN+i0+n)*256 + h];
    }
    for (int i = tid; i < NN*NHID; i += 256) {
        int n = i >> 7, h = i & 127;
        s_hy[n*129+h] = hxy[(size_t)(b*NN+n)*256 + 128 + h];
    }
    if (tid < NHID) s_w2[tid] = w2[tid];
    __syncthreads();
    for (int idx = tid; idx < 9*NN; idx += 256) {
        int il = idx / NN, j = idx - il*NN;
        const float* px = &s_hx[il*129];
        const float* py = &s_hy[j*129];
        float s = 0.f;
        #pragma unroll 8
        for (int h = 0; h < NHID; ++h) s += s_w2[h] * fmaxf(px[h] + py[h], 0.f);
        out_g[(size_t)b*NN*NN + (i0+il)*NN + j] = s;
    }
}

// ---------------------------------------------------------------------------
// iter_k: grid 128. C = out - out^T, 3 assignment iterations, final A
// row-softmax pre-scaled by sigmoid(att) -> A_g (128 x 36 x 36 f32).
// ---------------------------------------------------------------------------
__global__ __launch_bounds__(256) void iter_k(
    const float* __restrict__ out_g, const float* __restrict__ att,
    const float* __restrict__ lr, float* __restrict__ A_g)
{
    __shared__ float s_out[NN*S36], s_C[NN*S36], s_logits[NN*S36], s_P[NN*S36];
    __shared__ float s_sg[NN];
    int b = blockIdx.x, tid = threadIdx.x;
    for (int idx = tid; idx < NN*NN; idx += 256) {
        int i = idx / NN, j = idx - i*NN;
        s_out[i*S36+j] = out_g[(size_t)b*NN*NN + idx];
        s_logits[i*S36+j] = 0.f;
    }
    if (tid < NN) s_sg[tid] = sigf(att[b*NN + tid]);
    float lr_abs = fabsf(lr[0]);
    __syncthreads();
    for (int idx = tid; idx < NN*NN; idx += 256) {
        int i = idx / NN, j = idx - i*NN;
        s_C[i*S36+j] = s_out[i*S36+j] - s_out[j*S36+i];
    }
    __syncthreads();
    for (int it = 0; it < 3; ++it) {
        if (tid < NN) {
            int i = tid;
            float mx = -1e30f;
            for (int l = 0; l < NN; ++l) mx = fmaxf(mx, s_logits[i*S36+l]);
            float sum = 0.f;
            for (int l = 0; l < NN; ++l) { float e = expf(s_logits[i*S36+l]-mx); s_P[i*S36+l] = e; sum += e; }
            float inv = 1.f/sum;
            for (int l = 0; l < NN; ++l) s_P[i*S36+l] *= inv;
        }
        __syncthreads();
        if (tid < NN) {
            int l = tid;
            float S = 0.f;
            for (int i = 0; i < NN; ++i) S += s_P[i*S36+l];
            float cum = 0.f;
            for (int i = 0; i < NN; ++i) {
                float p = s_P[i*S36+l];
                cum += p;
                s_P[i*S36+l] = S - 2.f*cum + p;
            }
        }
        __syncthreads();
        for (int idx = tid; idx < NN*NN; idx += 256) {
            int i = idx / NN, j = idx - i*NN;
            float g = 0.f;
            #pragma unroll
            for (int l = 0; l < NN; ++l) g += s_P[i*S36+l] * s_C[j*S36+l];
            s_logits[i*S36+j] -= lr_abs * g;
        }
        __syncthreads();
    }
    if (tid < NN) {
        int i = tid;
        float mx = -1e30f;
        for (int l = 0; l < NN; ++l) mx = fmaxf(mx, s_logits[i*S36+l]);
        float sum = 0.f;
        for (int l = 0; l < NN; ++l) { float e = expf(s_logits[i*S36+l]-mx); s_P[i*S36+l] = e; sum += e; }
        float inv = 1.f/sum;
        for (int l = 0; l < NN; ++l)
            A_g[(size_t)b*NN*NN + i*NN + l] = s_P[i*S36+l] * inv * s_sg[l];
    }
}

// ---------------------------------------------------------------------------
// xseq_k: grid (128,2). xseq[i][b][c] = sum_l A[b][i][l]*feats[b][l][c], bf16.
// half 0: cols 0..255 (+512..543 for tid<32); half 1: cols 256..511.
// ---------------------------------------------------------------------------
__global__ __launch_bounds__(256) void xseq_k(
    const float* __restrict__ feats, const float* __restrict__ A_g,
    unsigned short* __restrict__ xseq)
{
    __shared__ float s_P[NN*S36];
    int b = blockIdx.x, half = blockIdx.y, tid = threadIdx.x;
    for (int idx = tid; idx < NN*NN; idx += 256) {
        int i = idx / NN, l = idx - i*NN;
        s_P[i*S36+l] = A_g[(size_t)b*NN*NN + idx];
    }
    __syncthreads();
    const float* fb = feats + (size_t)b*NN*NMID;
    int ncols = (half == 0 && tid < 32) ? 2 : 1;
    #pragma unroll
    for (int rep = 0; rep < 2; ++rep) {
        if (rep >= ncols) break;
        int c = (rep == 0) ? half*256 + tid : 512 + tid;
        float colv[NN];
        #pragma unroll
        for (int l = 0; l < NN; ++l) colv[l] = (c < NMID) ? fb[l*NMID + c] : 0.f;
        #pragma unroll 4
        for (int i = 0; i < NN; ++i) {
            float s = 0.f;
            #pragma unroll
            for (int l = 0; l < NN; ++l) s += s_P[i*S36+l] * colv[l];
            xseq[((size_t)i*NB + b)*KP + c] = f2bf(s);
        }
    }
}

// ---------------------------------------------------------------------------
// LSTM step v4b: grid 128 blocks, 256 thr. Block owns 32 gate-cols (8 units).
// whh slice (32x1024 bf16 = 64KB) cached in LDS ONCE, layout [kc][n][16B]
// (kc = 8-elem k-chunk, stride 512B). K-loop is barrier-free: A (=h)
// fragments read directly from global in MFMA layout (L2-hot).
// Cols unit-interleaved: col = u*4+g. xw has b_ih+b_hh folded.
// ---------------------------------------------------------------------------
__global__ __launch_bounds__(256) void lstm_step(
    const unsigned short* __restrict__ h_in, const unsigned short* __restrict__ whh,
    const unsigned short* __restrict__ xw_t, float* __restrict__ c,
    unsigned short* __restrict__ h_out)
{
    __shared__ __align__(16) char Bls[65536];   // [kc 0..127][n 0..31][16B]
    __shared__ float gates[128][36];            // stride 36 f32 = 144B (16B mult)
    int tid = threadIdx.x;
    int lane = tid & 63, wave = tid >> 6;
    int n0 = blockIdx.x * 32;
    // stage whh slice once
    #pragma unroll
    for (int r = 0; r < 16; ++r) {
        int idx = r*256 + tid;
        int kc = idx >> 5, n = idx & 31;
        uint4 v = *(const uint4*)(whh + (size_t)(n0+n)*NOUT + kc*8);
        *(uint4*)(Bls + kc*512 + n*16) = v;
    }
    __syncthreads();
    f32x4 acc[2][2];
    #pragma unroll
    for (int t = 0; t < 2; ++t)
        #pragma unroll
        for (int j = 0; j < 2; ++j) acc[t][j] = (f32x4){0.f,0.f,0.f,0.f};
    // A fragment: row = 32*wave + t*16 + (lane&15), k-chunk = k0/8 + (lane>>4)
    const unsigned short* hrow = h_in + (size_t)(32*wave + (lane&15))*NOUT + (lane>>4)*8;
    // B fragment: byte offset = (k0/8 + lane>>4)*512 + n_local*16
    const char* bbase = Bls + (lane>>4)*512 + (lane&15)*16;
    #pragma unroll 8
    for (int k0 = 0; k0 < NOUT; k0 += 32) {
        bf16x8 b0 = *(const bf16x8*)(bbase + (k0<<6));          // (k0>>3)*512
        bf16x8 b1 = *(const bf16x8*)(bbase + (k0<<6) + 256);    // n_local+16
        bf16x8 a0 = *(const bf16x8*)(hrow + k0);
        bf16x8 a1 = *(const bf16x8*)(hrow + 16*NOUT + k0);
        acc[0][0] = __builtin_amdgcn_mfma_f32_16x16x32_bf16(a0, b0, acc[0][0], 0, 0, 0);
        acc[0][1] = __builtin_amdgcn_mfma_f32_16x16x32_bf16(a0, b1, acc[0][1], 0, 0, 0);
        acc[1][0] = __builtin_amdgcn_mfma_f32_16x16x32_bf16(a1, b0, acc[1][0], 0, 0, 0);
        acc[1][1] = __builtin_amdgcn_mfma_f32_16x16x32_bf16(a1, b1, acc[1][1], 0, 0, 0);
    }
    int colf = lane & 15, rowq = lane >> 4;
    #pragma unroll
    for (int t = 0; t < 2; ++t)
        #pragma unroll
        for (int j = 0; j < 2; ++j)
            #pragma unroll
            for (int reg = 0; reg < 4; ++reg)
                gates[32*wave + t*16 + rowq*4 + reg][j*16 + colf] = acc[t][j][reg];
    __syncthreads();
    #pragma unroll
    for (int p = 0; p < 4; ++p) {
        int idx = p*256 + tid;        // 1024 = 128 batches x 8 units
        int ul = idx & 7, bb = idx >> 3;
        float4 gl = *(const float4*)&gates[bb][ul*4];
        uint2 xw2 = *(const uint2*)(xw_t + (size_t)bb*4*NOUT + n0 + ul*4);
        float g0 = gl.x + bf2f((unsigned short)(xw2.x & 0xffffu));
        float g1 = gl.y + bf2f((unsigned short)(xw2.x >> 16));
        float g2 = gl.z + bf2f((unsigned short)(xw2.y & 0xffffu));
        float g3 = gl.w + bf2f((unsigned short)(xw2.y >> 16));
        float ig = sigf(g0), fg = sigf(g1), gg = tanhf(g2), og = sigf(g3);
        size_t o = (size_t)bb*NOUT + (n0>>2) + ul;
        float cc = fg*c[o] + ig*gg;
        c[o] = cc;
        h_out[o] = f2bf(og*tanhf(cc));
    }
}

__global__ __launch_bounds__(256) void copy_out(const float* __restrict__ c, float* __restrict__ out)
{
    int i = blockIdx.x*256 + threadIdx.x;
    out[i] = c[i];
}

// ---------------------------------------------------------------------------
extern "C" void kernel_launch(void* const* d_in, const int* in_sizes, int n_in,
                              void* d_out, int out_size, void* d_ws, size_t ws_size,
                              hipStream_t stream) {
    (void)in_sizes; (void)n_in; (void)out_size; (void)ws_size;
    const float* boxes     = (const float*)d_in[0];
    const float* attention = (const float*)d_in[1];
    const float* features  = (const float*)d_in[2];
    const float* conv_w    = (const float*)d_in[3];
    const float* conv_b    = (const float*)d_in[4];
    const float* skew_wx   = (const float*)d_in[5];
    const float* skew_wy   = (const float*)d_in[6];
    const float* skew_b1   = (const float*)d_in[7];
    const float* skew_w2   = (const float*)d_in[8];
    // d_in[9] = skew_b2: cancels in C = out - out^T
    const float* w_ih      = (const float*)d_in[10];
    const float* w_hh      = (const float*)d_in[11];
    const float* b_ih      = (const float*)d_in[12];
    const float* b_hh      = (const float*)d_in[13];
    const float* lr        = (const float*)d_in[14];

    // workspace layout (bytes, all 256-aligned)
    char* ws = (char*)d_ws;
    float*          feats    = (float*)(ws);                      // 4608x517 f32   9,529,344
    float*          hxy      = (float*)(ws + 9529344);            // 4608x256 f32   4,718,592
    unsigned short* feats_bf = (unsigned short*)(ws + 14247936);  // 4608x544 bf16  5,013,504
    unsigned short* xseq_bf  = (unsigned short*)(ws + 19261440);  // 4608x544 bf16  5,013,504
    unsigned short* wih_il   = (unsigned short*)(ws + 24274944);  // 4096x544 bf16  4,456,448
    unsigned short* whh_il   = (unsigned short*)(ws + 28731392);  // 4096x1024 bf16 8,388,608
    unsigned short* wxy_bf   = (unsigned short*)(ws + 37120000);  // 256x544 bf16     278,528
    float*          comb_b   = (float*)(ws + 37398528);           // 4096 f32          16,384
    float*          hxy_b    = (float*)(ws + 37414912);           // 256 f32            1,024
    unsigned short* h0       = (unsigned short*)(ws + 37416192);  // 128x1024 bf16    262,144
    unsigned short* h1       = (unsigned short*)(ws + 37678336);  // 128x1024 bf16    262,144
    float*          cst      = (float*)(ws + 37940480);           // 128x1024 f32     524,288
    unsigned short* xw_bf    = (unsigned short*)(ws + 38464768);  // 4608x4096 bf16 37,748,736
    float*          out_g    = (float*)(ws + 76213504);           // 128x1296 f32     663,552
    float*          A_g      = (float*)(ws + 76877056);           // 128x1296 f32     663,552
    // features_bf / convw_bf overlap xw_bf region (dead before xw GEMM writes)
    unsigned short* features_bf = xw_bf;                          // 4608x2048 bf16
    unsigned short* convw_bf = (unsigned short*)(ws + 38464768 + 18874368); // 512x2048

    // prep
    fill_small<<<NB, 64, 0, stream>>>(boxes, attention, feats);
    cast_bf16<<<2048, 256, 0, stream>>>(features, features_bf, ROWS*NFEAT);
    cast_bf16<<<512, 256, 0, stream>>>(conv_w, convw_bf, 512*NFEAT);
    prep_wih<<<1024, 256, 0, stream>>>(w_ih, wih_il);
    prep_whh<<<2048, 256, 0, stream>>>(w_hh, whh_il);
    prep_misc<<<512, 256, 0, stream>>>(b_ih, b_hh, comb_b, h0, cst);
    build_wxy<<<128, 256, 0, stream>>>(skew_wx, skew_wy, skew_b1, wxy_bf, hxy_b);

    // conv: feats[:,5:517] = features . conv_w^T + conv_b
    gemm_mfma<<<dim3(8, 36), 256, 0, stream>>>(features_bf, convw_bf, conv_b,
                                               (void*)(feats + 5), NFEAT, NFEAT, NFEAT, NMID, 0);
    cast_pad<<<1024, 256, 0, stream>>>(feats, feats_bf, ROWS, NMID);
    // hxy = feats . [wx;wy]^T + [b1;0]
    gemm_mfma<<<dim3(4, 36), 256, 0, stream>>>(feats_bf, wxy_bf, hxy_b,
                                               (void*)hxy, KP, KP, KP, 256, 0);
    // assignment pipeline
    out_k<<<dim3(NB, 4), 256, 0, stream>>>(hxy, skew_w2, out_g);
    iter_k<<<NB, 256, 0, stream>>>(out_g, attention, lr, A_g);
    xseq_k<<<dim3(NB, 2), 256, 0, stream>>>(feats, A_g, xseq_bf);
    // xw = xseq . w_ih_il^T + (b_ih+b_hh)  -> bf16
    gemm_mfma<<<dim3(64, 36), 256, 0, stream>>>(xseq_bf, wih_il, comb_b,
                                                (void*)xw_bf, KP, KP, KP, 4*NOUT, 1);
    unsigned short* hbuf[2] = {h0, h1};
    for (int t = 0; t < NN; ++t) {
        lstm_step<<<NB, 256, 0, stream>>>(hbuf[t & 1], whh_il,
                                          xw_bf + (size_t)t*NB*4*NOUT, cst, hbuf[(t+1) & 1]);
    }
    copy_out<<<(NB*NOUT)/256, 256, 0, stream>>>(cst, (float*)d_out);
}

// Round 6
// 756.627 us; speedup vs baseline: 1.2931x; 1.2931x over previous
//
#include <hip/hip_runtime.h>
#include <math.h>

// Problem dims
#define NB 128
#define NN 36
#define S37 37            // padded stride (xseq_k)
#define S40 40            // padded stride, 16B-aligned rows (iter_k)
#define NFEAT 2048
#define NMID 517
#define KP 544            // padded K (multiple of 32) for MID-dim GEMMs
#define NHID 128
#define NOUT 1024
#define ROWS (NB*NN)      // 4608

typedef __bf16 bf16x8 __attribute__((ext_vector_type(8)));
typedef float  f32x4  __attribute__((ext_vector_type(4)));

__device__ __forceinline__ float sigf(float x){ return 1.f/(1.f+expf(-x)); }
__device__ __forceinline__ unsigned short f2bf(float x){
    unsigned u = __float_as_uint(x);
    return (unsigned short)((u + 0x7FFFu + ((u>>16)&1u)) >> 16);
}
__device__ __forceinline__ float bf2f(unsigned short b){
    return __uint_as_float(((unsigned)b) << 16);
}

// ---------------------------------------------------------------------------
// prep_all: ALL input casts/reorders/zeroing in one dispatch (was 7 kernels).
// ---------------------------------------------------------------------------
__global__ __launch_bounds__(256) void prep_all(
    const float* __restrict__ boxes, const float* __restrict__ att,
    const float* __restrict__ features, const float* __restrict__ conv_w,
    const float* __restrict__ wx, const float* __restrict__ wy,
    const float* __restrict__ b1, const float* __restrict__ w_ih,
    const float* __restrict__ w_hh, const float* __restrict__ b_ih,
    const float* __restrict__ b_hh,
    unsigned short* __restrict__ features_bf, unsigned short* __restrict__ convw_bf,
    unsigned short* __restrict__ wxy_bf, float* __restrict__ hxy_b,
    unsigned short* __restrict__ wih_il, unsigned short* __restrict__ whh_il,
    float* __restrict__ comb_b, unsigned short* __restrict__ h0,
    float* __restrict__ c, float* __restrict__ feats)
{
    int gtid = blockIdx.x*256 + threadIdx.x;
    int gs = gridDim.x*256;
    // box normalize + att -> feats cols 0..4 (128 waves)
    if (gtid < 128*64) {
        int b = gtid >> 6, t = gtid & 63;
        float mx = -1e30f;
        for (int idx = t; idx < 4*NN; idx += 64) mx = fmaxf(mx, boxes[b*4*NN + idx]);
        for (int off = 32; off > 0; off >>= 1) mx = fmaxf(mx, __shfl_down(mx, off));
        mx = __shfl(mx, 0);
        float inv = 1.f / mx;
        for (int idx = t; idx < 4*NN; idx += 64) {
            int r = idx / NN, n = idx - r*NN;
            feats[(size_t)(b*NN+n)*NMID + r] = boxes[b*4*NN + idx] * inv;
        }
        if (t < NN) feats[(size_t)(b*NN+t)*NMID + 4] = att[b*NN + t];
    }
    for (int i = gtid; i < ROWS*NFEAT; i += gs) features_bf[i] = f2bf(features[i]);
    for (int i = gtid; i < 512*NFEAT; i += gs) convw_bf[i] = f2bf(conv_w[i]);
    for (int i = gtid; i < 256*KP; i += gs) {
        int r = i / KP, k = i - r*KP;
        float v = 0.f;
        if (k < NMID) v = (r < NHID) ? wx[(size_t)r*NMID+k] : wy[(size_t)(r-NHID)*NMID+k];
        wxy_bf[i] = f2bf(v);
    }
    for (int i = gtid; i < 256; i += gs) hxy_b[i] = (i < NHID) ? b1[i] : 0.f;
    for (int i = gtid; i < 4*NOUT*KP; i += gs) {
        int row = i / KP, k = i - row*KP;
        int u = row >> 2, g = row & 3;
        wih_il[i] = (k < NMID) ? f2bf(w_ih[(size_t)(g*NOUT+u)*NMID + k]) : (unsigned short)0;
    }
    for (int i = gtid; i < 4*NOUT*NOUT; i += gs) {
        int row = i >> 10, k = i & 1023;
        int u = row >> 2, g = row & 3;
        whh_il[i] = f2bf(w_hh[(size_t)(g*NOUT+u)*NOUT + k]);
    }
    for (int i = gtid; i < 4*NOUT; i += gs) {
        int u = i >> 2, g = i & 3;
        comb_b[i] = b_ih[g*NOUT+u] + b_hh[g*NOUT+u];
    }
    for (int i = gtid; i < NB*NOUT; i += gs) { h0[i] = 0; c[i] = 0.f; }
}

// ---------------------------------------------------------------------------
// conv split-K GEMM: grid (8, 36, 4). Tile 128x64, K-slice 512.
// part[z][r][c] = sum_{k in slice z} features_bf[m0+r][k]*convw_bf[n0+c][k]
// ---------------------------------------------------------------------------
__global__ __launch_bounds__(256) void conv_sk(
    const unsigned short* __restrict__ A, const unsigned short* __restrict__ B,
    float* __restrict__ part)
{
    __shared__ __align__(16) char As[8192];
    __shared__ __align__(16) char Bs[4096];
    int m0 = blockIdx.y * 128, n0 = blockIdx.x * 64;
    int kbeg = blockIdx.z * 512;
    int tid = threadIdx.x;
    int lane = tid & 63, wave = tid >> 6;
    int wm = wave >> 1, wn = wave & 1;
    f32x4 acc[4][2];
    #pragma unroll
    for (int i = 0; i < 4; ++i)
        #pragma unroll
        for (int j = 0; j < 2; ++j) acc[i][j] = (f32x4){0.f,0.f,0.f,0.f};

    for (int k0 = 0; k0 < 512; k0 += 32) {
        #pragma unroll
        for (int cc = tid; cc < 512; cc += 256) {
            int r = cc >> 2, q = cc & 3;
            uint4 v = *(const uint4*)(A + (size_t)(m0+r)*NFEAT + kbeg + k0 + q*8);
            *(uint4*)(As + ((r>>4)<<10) + (q<<8) + ((r&15)<<4)) = v;
        }
        {
            int r = tid >> 2, q = tid & 3;
            uint4 v = *(const uint4*)(B + (size_t)(n0+r)*NFEAT + kbeg + k0 + q*8);
            *(uint4*)(Bs + ((r>>4)<<10) + (q<<8) + ((r&15)<<4)) = v;
        }
        __syncthreads();
        bf16x8 af[4], bfr[2];
        #pragma unroll
        for (int i = 0; i < 4; ++i) af[i]  = *(bf16x8*)(As + ((wm*4+i)<<10) + (lane<<4));
        #pragma unroll
        for (int j = 0; j < 2; ++j) bfr[j] = *(bf16x8*)(Bs + ((wn*2+j)<<10) + (lane<<4));
        #pragma unroll
        for (int i = 0; i < 4; ++i)
            #pragma unroll
            for (int j = 0; j < 2; ++j)
                acc[i][j] = __builtin_amdgcn_mfma_f32_16x16x32_bf16(af[i], bfr[j], acc[i][j], 0, 0, 0);
        __syncthreads();
    }
    float* out = part + (size_t)blockIdx.z * ROWS * 512;
    int colf = lane & 15, rowq = lane >> 4;
    #pragma unroll
    for (int j = 0; j < 2; ++j) {
        int col = n0 + (wn*2+j)*16 + colf;
        #pragma unroll
        for (int i = 0; i < 4; ++i)
            #pragma unroll
            for (int reg = 0; reg < 4; ++reg) {
                int row = m0 + (wm*4+i)*16 + rowq*4 + reg;
                out[(size_t)row*512 + col] = acc[i][j][reg];
            }
    }
}

// ---------------------------------------------------------------------------
// conv_reduce: feats[:,5:] = sum_z part[z] + conv_b; also emits the FULL
// padded bf16 feats (cols 0..4 from feats, 5..516 computed, 517..543 zero).
// ---------------------------------------------------------------------------
__global__ __launch_bounds__(256) void conv_reduce(
    const float* __restrict__ part, const float* __restrict__ bias,
    float* __restrict__ feats, unsigned short* __restrict__ feats_bf)
{
    int gtid = blockIdx.x*256 + threadIdx.x;
    int gs = gridDim.x*256;
    const size_t PS = (size_t)ROWS * 512;
    for (int i = gtid; i < ROWS*512; i += gs) {
        int r = i >> 9, cc = i & 511;
        float s = part[i] + part[PS+i] + part[2*PS+i] + part[3*PS+i] + bias[cc];
        feats[(size_t)r*NMID + 5 + cc] = s;
        feats_bf[(size_t)r*KP + 5 + cc] = f2bf(s);
    }
    for (int i = gtid; i < ROWS*5; i += gs) {
        int r = i / 5, cc = i - r*5;
        feats_bf[(size_t)r*KP + cc] = f2bf(feats[(size_t)r*NMID + cc]);
    }
    for (int i = gtid; i < ROWS*27; i += gs) {
        int r = i / 27, cc = i - r*27;
        feats_bf[(size_t)r*KP + 517 + cc] = 0;
    }
}

// ---------------------------------------------------------------------------
// bf16 MFMA GEMM: C[m,n] = sum_k A[m,k]*B[n,k] + bias[n]
// Block tile 128x64, 256 thr = 4 waves (2x2), wave tile 64x32. (hxy, xw)
// ---------------------------------------------------------------------------
__global__ __launch_bounds__(256) void gemm_mfma(
    const unsigned short* __restrict__ A, const unsigned short* __restrict__ B,
    const float* __restrict__ bias, void* __restrict__ Cp,
    int K, int lda, int ldb, int ldc, int obf)
{
    __shared__ __align__(16) char As[8192];
    __shared__ __align__(16) char Bs[4096];
    int m0 = blockIdx.y * 128, n0 = blockIdx.x * 64;
    int tid = threadIdx.x;
    int lane = tid & 63, wave = tid >> 6;
    int wm = wave >> 1, wn = wave & 1;
    f32x4 acc[4][2];
    #pragma unroll
    for (int i = 0; i < 4; ++i)
        #pragma unroll
        for (int j = 0; j < 2; ++j) acc[i][j] = (f32x4){0.f,0.f,0.f,0.f};

    for (int k0 = 0; k0 < K; k0 += 32) {
        #pragma unroll
        for (int cc = tid; cc < 512; cc += 256) {
            int r = cc >> 2, q = cc & 3;
            uint4 v = *(const uint4*)(A + (size_t)(m0+r)*lda + k0 + q*8);
            *(uint4*)(As + ((r>>4)<<10) + (q<<8) + ((r&15)<<4)) = v;
        }
        {
            int r = tid >> 2, q = tid & 3;
            uint4 v = *(const uint4*)(B + (size_t)(n0+r)*ldb + k0 + q*8);
            *(uint4*)(Bs + ((r>>4)<<10) + (q<<8) + ((r&15)<<4)) = v;
        }
        __syncthreads();
        bf16x8 af[4], bfr[2];
        #pragma unroll
        for (int i = 0; i < 4; ++i) af[i]  = *(bf16x8*)(As + ((wm*4+i)<<10) + (lane<<4));
        #pragma unroll
        for (int j = 0; j < 2; ++j) bfr[j] = *(bf16x8*)(Bs + ((wn*2+j)<<10) + (lane<<4));
        #pragma unroll
        for (int i = 0; i < 4; ++i)
            #pragma unroll
            for (int j = 0; j < 2; ++j)
                acc[i][j] = __builtin_amdgcn_mfma_f32_16x16x32_bf16(af[i], bfr[j], acc[i][j], 0, 0, 0);
        __syncthreads();
    }
    int colf = lane & 15, rowq = lane >> 4;
    #pragma unroll
    for (int j = 0; j < 2; ++j) {
        int col = n0 + (wn*2+j)*16 + colf;
        float bv = bias ? bias[col] : 0.f;
        #pragma unroll
        for (int i = 0; i < 4; ++i) {
            #pragma unroll
            for (int reg = 0; reg < 4; ++reg) {
                int row = m0 + (wm*4+i)*16 + rowq*4 + reg;
                float v = acc[i][j][reg] + bv;
                if (obf) ((unsigned short*)Cp)[(size_t)row*ldc + col] = f2bf(v);
                else     ((float*)Cp)[(size_t)row*ldc + col] = v;
            }
        }
    }
}

// ---------------------------------------------------------------------------
// out_k: grid (128,4). Block (b,s) computes rows i0=s*9..s*9+8 of
// out[b][i][j] = sum_h w2[h]*relu(hx[i][h]+hy[j][h]) -> global f32.
// ---------------------------------------------------------------------------
__global__ __launch_bounds__(256) void out_k(
    const float* __restrict__ hxy, const float* __restrict__ w2,
    float* __restrict__ out_g)
{
    __shared__ float s_hx[9*129], s_hy[NN*129], s_w2[NHID];
    int b = blockIdx.x, i0 = blockIdx.y * 9, tid = threadIdx.x;
    for (int i = tid; i < 9*NHID; i += 256) {
        int n = i >> 7, h = i & 127;
        s_hx[n*129+h] = hxy[(size_t)(b*NN+i0+n)*256 + h];
    }
    for (int i = tid; i < NN*NHID; i += 256) {
        int n = i >> 7, h = i & 127;
        s_hy[n*129+h] = hxy[(size_t)(b*NN+n)*256 + 128 + h];
    }
    if (tid < NHID) s_w2[tid] = w2[tid];
    __syncthreads();
    for (int idx = tid; idx < 9*NN; idx += 256) {
        int il = idx / NN, j = idx - il*NN;
        const float* px = &s_hx[il*129];
        const float* py = &s_hy[j*129];
        float s = 0.f;
        #pragma unroll 8
        for (int h = 0; h < NHID; ++h) s += s_w2[h] * fmaxf(px[h] + py[h], 0.f);
        out_g[(size_t)b*NN*NN + (i0+il)*NN + j] = s;
    }
}

// ---------------------------------------------------------------------------
// iter_k: grid 128. C = out - out^T, 3 assignment iterations, final A
// row-softmax pre-scaled by sigmoid(att) -> A_g. Stride 40 -> float4 rows.
// ---------------------------------------------------------------------------
__global__ __launch_bounds__(256) void iter_k(
    const float* __restrict__ out_g, const float* __restrict__ att,
    const float* __restrict__ lr, float* __restrict__ A_g)
{
    __shared__ __align__(16) float s_out[NN*S40], s_C[NN*S40], s_logits[NN*S40], s_P[NN*S40];
    __shared__ float s_sg[NN];
    int b = blockIdx.x, tid = threadIdx.x;
    for (int idx = tid; idx < NN*NN; idx += 256) {
        int i = idx / NN, j = idx - i*NN;
        s_out[i*S40+j] = out_g[(size_t)b*NN*NN + idx];
        s_logits[i*S40+j] = 0.f;
    }
    if (tid < NN) s_sg[tid] = sigf(att[b*NN + tid]);
    float lr_abs = fabsf(lr[0]);
    __syncthreads();
    for (int idx = tid; idx < NN*NN; idx += 256) {
        int i = idx / NN, j = idx - i*NN;
        s_C[i*S40+j] = s_out[i*S40+j] - s_out[j*S40+i];
    }
    __syncthreads();
    for (int it = 0; it < 3; ++it) {
        if (tid < NN) {
            int i = tid;
            float mx = -1e30f;
            for (int l = 0; l < NN; ++l) mx = fmaxf(mx, s_logits[i*S40+l]);
            float sum = 0.f;
            for (int l = 0; l < NN; ++l) { float e = expf(s_logits[i*S40+l]-mx); s_P[i*S40+l] = e; sum += e; }
            float inv = 1.f/sum;
            for (int l = 0; l < NN; ++l) s_P[i*S40+l] *= inv;
        }
        __syncthreads();
        if (tid < NN) {
            int l = tid;
            float S = 0.f;
            for (int i = 0; i < NN; ++i) S += s_P[i*S40+l];
            float cum = 0.f;
            for (int i = 0; i < NN; ++i) {
                float p = s_P[i*S40+l];
                cum += p;
                s_P[i*S40+l] = S - 2.f*cum + p;
            }
        }
        __syncthreads();
        for (int idx = tid; idx < NN*NN; idx += 256) {
            int i = idx / NN, j = idx - i*NN;
            const f32x4* Pp = (const f32x4*)&s_P[i*S40];
            const f32x4* Cc = (const f32x4*)&s_C[j*S40];
            float g = 0.f;
            #pragma unroll
            for (int q = 0; q < 9; ++q) {      // 9*4 = 36 exactly
                f32x4 a = Pp[q], bb = Cc[q];
                g += a[0]*bb[0] + a[1]*bb[1] + a[2]*bb[2] + a[3]*bb[3];
            }
            s_logits[i*S40+j] -= lr_abs * g;
        }
        __syncthreads();
    }
    if (tid < NN) {
        int i = tid;
        float mx = -1e30f;
        for (int l = 0; l < NN; ++l) mx = fmaxf(mx, s_logits[i*S40+l]);
        float sum = 0.f;
        for (int l = 0; l < NN; ++l) { float e = expf(s_logits[i*S40+l]-mx); s_P[i*S40+l] = e; sum += e; }
        float inv = 1.f/sum;
        for (int l = 0; l < NN; ++l)
            A_g[(size_t)b*NN*NN + i*NN + l] = s_P[i*S40+l] * inv * s_sg[l];
    }
}

// ---------------------------------------------------------------------------
// xseq_k: grid (128,2). xseq[i][b][c] = sum_l A[b][i][l]*feats[b][l][c], bf16.
// ---------------------------------------------------------------------------
__global__ __launch_bounds__(256) void xseq_k(
    const float* __restrict__ feats, const float* __restrict__ A_g,
    unsigned short* __restrict__ xseq)
{
    __shared__ float s_P[NN*S37];
    int b = blockIdx.x, half = blockIdx.y, tid = threadIdx.x;
    for (int idx = tid; idx < NN*NN; idx += 256) {
        int i = idx / NN, l = idx - i*NN;
        s_P[i*S37+l] = A_g[(size_t)b*NN*NN + idx];
    }
    __syncthreads();
    const float* fb = feats + (size_t)b*NN*NMID;
    int ncols = (half == 0 && tid < 32) ? 2 : 1;
    #pragma unroll
    for (int rep = 0; rep < 2; ++rep) {
        if (rep >= ncols) break;
        int c = (rep == 0) ? half*256 + tid : 512 + tid;
        float colv[NN];
        #pragma unroll
        for (int l = 0; l < NN; ++l) colv[l] = (c < NMID) ? fb[l*NMID + c] : 0.f;
        #pragma unroll 4
        for (int i = 0; i < NN; ++i) {
            float s = 0.f;
            #pragma unroll
            for (int l = 0; l < NN; ++l) s += s_P[i*S37+l] * colv[l];
            xseq[((size_t)i*NB + b)*KP + c] = f2bf(s);
        }
    }
}

// ---------------------------------------------------------------------------
// LSTM step v5: grid 256 = 4 batch-tiles x 64 col-tiles; 256 thr = 4 waves.
// Block: 32 batches x 64 gate-cols (16 units). whh slice (64x1024 bf16 =
// 128KB) staged to LDS (L2-resident across steps: same blockIdx -> same XCD).
// K-loop per wave: (wm=wave&1 m-tile, wn=wave>>1 n-pair), 32 iters x 2 MFMA.
// Cols unit-interleaved (col = u*4+g). xw has b_ih+b_hh folded.
// Final step (cout != null) writes c straight to d_out.
// ---------------------------------------------------------------------------
__global__ __launch_bounds__(256) void lstm_step(
    const unsigned short* __restrict__ h_in, const unsigned short* __restrict__ whh,
    const unsigned short* __restrict__ xw_t, float* __restrict__ c,
    unsigned short* __restrict__ h_out, float* __restrict__ cout)
{
    __shared__ __align__(16) char Bls[131072];   // [kc 0..127][n 0..63][16B]
    __shared__ float gates[32][68];              // 68 f32 = 272B (16B multiple)
    int tid = threadIdx.x, lane = tid & 63, wave = tid >> 6;
    int blk = blockIdx.x;
    int m0 = (blk >> 6) * 32;          // batch tile
    int n0 = (blk & 63) * 64;          // gate-col tile (16 units)
    // stage whh slice: 64 rows x 128 k-chunks of 16B
    #pragma unroll
    for (int r = 0; r < 32; ++r) {
        int idx = r*256 + tid;
        int kc = idx >> 6, n = idx & 63;
        uint4 v = *(const uint4*)(whh + (size_t)(n0+n)*NOUT + kc*8);
        *(uint4*)(Bls + kc*1024 + n*16) = v;
    }
    __syncthreads();
    int wm = wave & 1, wn = wave >> 1;
    const char* bbase = Bls + (lane>>4)*1024 + wn*512 + (lane&15)*16;
    const unsigned short* hrow = h_in + (size_t)(m0 + wm*16 + (lane&15))*NOUT + (lane>>4)*8;
    f32x4 acc0 = (f32x4){0.f,0.f,0.f,0.f};
    f32x4 acc1 = (f32x4){0.f,0.f,0.f,0.f};
    #pragma unroll 8
    for (int k0 = 0; k0 < NOUT; k0 += 32) {
        bf16x8 a  = *(const bf16x8*)(hrow + k0);
        bf16x8 b0 = *(const bf16x8*)(bbase + (k0<<7));         // (k0/8)*1024
        bf16x8 b1 = *(const bf16x8*)(bbase + (k0<<7) + 256);   // next 16 cols
        acc0 = __builtin_amdgcn_mfma_f32_16x16x32_bf16(a, b0, acc0, 0, 0, 0);
        acc1 = __builtin_amdgcn_mfma_f32_16x16x32_bf16(a, b1, acc1, 0, 0, 0);
    }
    int colf = lane & 15, rowq = lane >> 4;
    #pragma unroll
    for (int reg = 0; reg < 4; ++reg) {
        gates[wm*16 + rowq*4 + reg][wn*32 + colf]      = acc0[reg];
        gates[wm*16 + rowq*4 + reg][wn*32 + 16 + colf] = acc1[reg];
    }
    __syncthreads();
    // epilogue: 32 batches x 16 units = 512 pairs, 2/thread
    #pragma unroll
    for (int p = 0; p < 2; ++p) {
        int idx = p*256 + tid;
        int ul = idx & 15, bl = idx >> 4;
        int b = m0 + bl, u = (n0 >> 2) + ul;
        float4 gl = *(const float4*)&gates[bl][ul*4];
        uint2 xw2 = *(const uint2*)(xw_t + (size_t)b*4*NOUT + n0 + ul*4);
        float g0 = gl.x + bf2f((unsigned short)(xw2.x & 0xffffu));
        float g1 = gl.y + bf2f((unsigned short)(xw2.x >> 16));
        float g2 = gl.z + bf2f((unsigned short)(xw2.y & 0xffffu));
        float g3 = gl.w + bf2f((unsigned short)(xw2.y >> 16));
        float ig = sigf(g0), fg = sigf(g1), gg = tanhf(g2), og = sigf(g3);
        size_t o = (size_t)b*NOUT + u;
        float cc = fg*c[o] + ig*gg;
        c[o] = cc;
        if (cout) cout[o] = cc;
        else      h_out[o] = f2bf(og*tanhf(cc));
    }
}

// ---------------------------------------------------------------------------
extern "C" void kernel_launch(void* const* d_in, const int* in_sizes, int n_in,
                              void* d_out, int out_size, void* d_ws, size_t ws_size,
                              hipStream_t stream) {
    (void)in_sizes; (void)n_in; (void)out_size; (void)ws_size;
    const float* boxes     = (const float*)d_in[0];
    const float* attention = (const float*)d_in[1];
    const float* features  = (const float*)d_in[2];
    const float* conv_w    = (const float*)d_in[3];
    const float* conv_b    = (const float*)d_in[4];
    const float* skew_wx   = (const float*)d_in[5];
    const float* skew_wy   = (const float*)d_in[6];
    const float* skew_b1   = (const float*)d_in[7];
    const float* skew_w2   = (const float*)d_in[8];
    // d_in[9] = skew_b2: cancels in C = out - out^T
    const float* w_ih      = (const float*)d_in[10];
    const float* w_hh      = (const float*)d_in[11];
    const float* b_ih      = (const float*)d_in[12];
    const float* b_hh      = (const float*)d_in[13];
    const float* lr        = (const float*)d_in[14];

    // workspace layout (bytes, 256-aligned). part (conv split-K partials,
    // 37.75MB) and xw_bf (same size) share region 0 — partials are dead
    // before the xw GEMM writes.
    char* ws = (char*)d_ws;
    float*          part     = (float*)(ws);                      // 4x4608x512 f32  37,748,736
    unsigned short* xw_bf    = (unsigned short*)(ws);             // 4608x4096 bf16 (same region)
    unsigned short* features_bf = (unsigned short*)(ws + 37748736); // 18,874,368
    unsigned short* convw_bf = (unsigned short*)(ws + 56623104);  //  2,097,152
    float*          feats    = (float*)(ws + 58720256);           //  9,529,344
    float*          hxy      = (float*)(ws + 68249600);           //  4,718,592
    unsigned short* feats_bf = (unsigned short*)(ws + 72968192);  //  5,013,504
    unsigned short* xseq_bf  = (unsigned short*)(ws + 77981696);  //  5,013,504
    unsigned short* wih_il   = (unsigned short*)(ws + 82995200);  //  4,456,448
    unsigned short* whh_il   = (unsigned short*)(ws + 87451648);  //  8,388,608
    unsigned short* wxy_bf   = (unsigned short*)(ws + 95840256);  //    278,528
    float*          comb_b   = (float*)(ws + 96118784);           //     16,384
    float*          hxy_b    = (float*)(ws + 96135168);           //      1,024
    unsigned short* h0       = (unsigned short*)(ws + 96136192);  //    262,144
    unsigned short* h1       = (unsigned short*)(ws + 96398336);  //    262,144
    float*          out_g    = (float*)(ws + 96660480);           //    663,552
    float*          A_g      = (float*)(ws + 97324032);           //    663,552
    float*          cst      = (float*)(ws + 97987584);           //    524,288
    // end: 98,511,872

    prep_all<<<2048, 256, 0, stream>>>(boxes, attention, features, conv_w,
                                       skew_wx, skew_wy, skew_b1, w_ih, w_hh,
                                       b_ih, b_hh, features_bf, convw_bf,
                                       wxy_bf, hxy_b, wih_il, whh_il, comb_b,
                                       h0, cst, feats);
    // conv split-K: partials then fused reduce+cast (produces feats + feats_bf)
    conv_sk<<<dim3(8, 36, 4), 256, 0, stream>>>(features_bf, convw_bf, part);
    conv_reduce<<<2048, 256, 0, stream>>>(part, conv_b, feats, feats_bf);
    // hxy = feats . [wx;wy]^T + [b1;0]
    gemm_mfma<<<dim3(4, 36), 256, 0, stream>>>(feats_bf, wxy_bf, hxy_b,
                                               (void*)hxy, KP, KP, KP, 256, 0);
    // assignment pipeline
    out_k<<<dim3(NB, 4), 256, 0, stream>>>(hxy, skew_w2, out_g);
    iter_k<<<NB, 256, 0, stream>>>(out_g, attention, lr, A_g);
    xseq_k<<<dim3(NB, 2), 256, 0, stream>>>(feats, A_g, xseq_bf);
    // xw = xseq . w_ih_il^T + (b_ih+b_hh)  -> bf16 (overwrites part region)
    gemm_mfma<<<dim3(64, 36), 256, 0, stream>>>(xseq_bf, wih_il, comb_b,
                                                (void*)xw_bf, KP, KP, KP, 4*NOUT, 1);
    unsigned short* hbuf[2] = {h0, h1};
    for (int t = 0; t < NN; ++t) {
        float* co = (t == NN-1) ? (float*)d_out : nullptr;
        lstm_step<<<256, 256, 0, stream>>>(hbuf[t & 1], whh_il,
                                           xw_bf + (size_t)t*NB*4*NOUT, cst,
                                           hbuf[(t+1) & 1], co);
    }
}

// Round 7
// 708.359 us; speedup vs baseline: 1.3812x; 1.0681x over previous
//
#include <hip/hip_runtime.h>
#include <math.h>

// Problem dims
#define NB 128
#define NN 36
#define S37 37            // padded stride (xseq_k)
#define S40 40            // padded stride, 16B-aligned rows (iter_k)
#define NFEAT 2048
#define NMID 517
#define KP 544            // padded K (multiple of 32) for MID-dim GEMMs
#define NHID 128
#define NOUT 1024
#define ROWS (NB*NN)      // 4608

typedef __bf16 bf16x8 __attribute__((ext_vector_type(8)));
typedef float  f32x4  __attribute__((ext_vector_type(4)));

__device__ __forceinline__ float sigf(float x){ return 1.f/(1.f+expf(-x)); }
__device__ __forceinline__ unsigned short f2bf(float x){
    unsigned u = __float_as_uint(x);
    return (unsigned short)((u + 0x7FFFu + ((u>>16)&1u)) >> 16);
}
__device__ __forceinline__ float bf2f(unsigned short b){
    return __uint_as_float(((unsigned)b) << 16);
}

// ---------------------------------------------------------------------------
// prep_all: ALL input casts/reorders/zeroing in one dispatch.
// ---------------------------------------------------------------------------
__global__ __launch_bounds__(256) void prep_all(
    const float* __restrict__ boxes, const float* __restrict__ att,
    const float* __restrict__ features, const float* __restrict__ conv_w,
    const float* __restrict__ wx, const float* __restrict__ wy,
    const float* __restrict__ b1, const float* __restrict__ w_ih,
    const float* __restrict__ w_hh, const float* __restrict__ b_ih,
    const float* __restrict__ b_hh,
    unsigned short* __restrict__ features_bf, unsigned short* __restrict__ convw_bf,
    unsigned short* __restrict__ wxy_bf, float* __restrict__ hxy_b,
    unsigned short* __restrict__ wih_il, unsigned short* __restrict__ whh_il,
    float* __restrict__ comb_b, unsigned short* __restrict__ h0,
    float* __restrict__ c, float* __restrict__ feats)
{
    int gtid = blockIdx.x*256 + threadIdx.x;
    int gs = gridDim.x*256;
    if (gtid < 128*64) {
        int b = gtid >> 6, t = gtid & 63;
        float mx = -1e30f;
        for (int idx = t; idx < 4*NN; idx += 64) mx = fmaxf(mx, boxes[b*4*NN + idx]);
        for (int off = 32; off > 0; off >>= 1) mx = fmaxf(mx, __shfl_down(mx, off));
        mx = __shfl(mx, 0);
        float inv = 1.f / mx;
        for (int idx = t; idx < 4*NN; idx += 64) {
            int r = idx / NN, n = idx - r*NN;
            feats[(size_t)(b*NN+n)*NMID + r] = boxes[b*4*NN + idx] * inv;
        }
        if (t < NN) feats[(size_t)(b*NN+t)*NMID + 4] = att[b*NN + t];
    }
    for (int i = gtid; i < ROWS*NFEAT; i += gs) features_bf[i] = f2bf(features[i]);
    for (int i = gtid; i < 512*NFEAT; i += gs) convw_bf[i] = f2bf(conv_w[i]);
    for (int i = gtid; i < 256*KP; i += gs) {
        int r = i / KP, k = i - r*KP;
        float v = 0.f;
        if (k < NMID) v = (r < NHID) ? wx[(size_t)r*NMID+k] : wy[(size_t)(r-NHID)*NMID+k];
        wxy_bf[i] = f2bf(v);
    }
    for (int i = gtid; i < 256; i += gs) hxy_b[i] = (i < NHID) ? b1[i] : 0.f;
    for (int i = gtid; i < 4*NOUT*KP; i += gs) {
        int row = i / KP, k = i - row*KP;
        int u = row >> 2, g = row & 3;
        wih_il[i] = (k < NMID) ? f2bf(w_ih[(size_t)(g*NOUT+u)*NMID + k]) : (unsigned short)0;
    }
    for (int i = gtid; i < 4*NOUT*NOUT; i += gs) {
        int row = i >> 10, k = i & 1023;
        int u = row >> 2, g = row & 3;
        whh_il[i] = f2bf(w_hh[(size_t)(g*NOUT+u)*NOUT + k]);
    }
    for (int i = gtid; i < 4*NOUT; i += gs) {
        int u = i >> 2, g = i & 3;
        comb_b[i] = b_ih[g*NOUT+u] + b_hh[g*NOUT+u];
    }
    for (int i = gtid; i < NB*NOUT; i += gs) { h0[i] = 0; c[i] = 0.f; }
}

// ---------------------------------------------------------------------------
// gemm128: C[m,n] = sum_k A[m,k]*B[n,k] (+ bias). Block tile 128x128,
// 4 waves = 2x2, wave tile 64x64 (16 MFMA / 8 ds_read_b128 per iter).
// XOR-swizzled LDS (r' = r ^ (q<<2)) -> conflict-free stores AND reads.
// Optional split-K via blockIdx.z: kbeg = z*Ksl, f32 partial out at
// Cp + z*pstride (bias ignored when pstride > 0 path uses obf=0,bias=null).
// ---------------------------------------------------------------------------
__global__ __launch_bounds__(256) void gemm128(
    const unsigned short* __restrict__ A, const unsigned short* __restrict__ B,
    const float* __restrict__ bias, void* __restrict__ Cp,
    int Ksl, int lda, int ldb, int ldc, int obf, long long pstride)
{
    __shared__ __align__(16) char As[16384];   // 8 mtiles x 2KB? no: 8 x 1KB x ... 128r x 32k x 2B = 8KB
    __shared__ __align__(16) char Bs[16384];
    int m0 = blockIdx.y * 128, n0 = blockIdx.x * 128;
    int kbeg = blockIdx.z * Ksl;
    int tid = threadIdx.x;
    int lane = tid & 63, wave = tid >> 6;
    int wm = wave >> 1, wn = wave & 1;
    int sw = ((lane>>4)<<8) + (((lane&15) ^ ((lane>>4)<<2))<<4);
    f32x4 acc[4][4];
    #pragma unroll
    for (int i = 0; i < 4; ++i)
        #pragma unroll
        for (int j = 0; j < 4; ++j) acc[i][j] = (f32x4){0.f,0.f,0.f,0.f};

    for (int k0 = 0; k0 < Ksl; k0 += 32) {
        #pragma unroll
        for (int p = 0; p < 2; ++p) {
            int cc = p*256 + tid;
            int r = cc >> 2, q = cc & 3;
            int sa = ((r>>4)<<10) + (q<<8) + ((((r&15) ^ (q<<2)))<<4);
            uint4 va = *(const uint4*)(A + (size_t)(m0+r)*lda + kbeg + k0 + q*8);
            *(uint4*)(As + sa) = va;
            uint4 vb = *(const uint4*)(B + (size_t)(n0+r)*ldb + kbeg + k0 + q*8);
            *(uint4*)(Bs + sa) = vb;
        }
        __syncthreads();
        bf16x8 af[4], bfr[4];
        #pragma unroll
        for (int i = 0; i < 4; ++i) af[i]  = *(bf16x8*)(As + ((wm*4+i)<<10) + sw);
        #pragma unroll
        for (int j = 0; j < 4; ++j) bfr[j] = *(bf16x8*)(Bs + ((wn*4+j)<<10) + sw);
        #pragma unroll
        for (int i = 0; i < 4; ++i)
            #pragma unroll
            for (int j = 0; j < 4; ++j)
                acc[i][j] = __builtin_amdgcn_mfma_f32_16x16x32_bf16(af[i], bfr[j], acc[i][j], 0, 0, 0);
        __syncthreads();
    }
    int colf = lane & 15, rowq = lane >> 4;
    #pragma unroll
    for (int j = 0; j < 4; ++j) {
        int col = n0 + (wn*4+j)*16 + colf;
        float bv = bias ? bias[col] : 0.f;
        #pragma unroll
        for (int i = 0; i < 4; ++i) {
            #pragma unroll
            for (int reg = 0; reg < 4; ++reg) {
                int row = m0 + (wm*4+i)*16 + rowq*4 + reg;
                float v = acc[i][j][reg] + bv;
                if (obf) ((unsigned short*)Cp)[(size_t)row*ldc + col] = f2bf(v);
                else ((float*)Cp + (size_t)blockIdx.z*pstride)[(size_t)row*ldc + col] = v;
            }
        }
    }
}

// ---------------------------------------------------------------------------
// conv_reduce: feats[:,5:] = sum_z part[z] + conv_b; emits full padded bf16
// feats (cols 0..4 from feats, 5..516 computed, 517..543 zero).
// ---------------------------------------------------------------------------
__global__ __launch_bounds__(256) void conv_reduce(
    const float* __restrict__ part, const float* __restrict__ bias,
    float* __restrict__ feats, unsigned short* __restrict__ feats_bf)
{
    int gtid = blockIdx.x*256 + threadIdx.x;
    int gs = gridDim.x*256;
    const size_t PS = (size_t)ROWS * 512;
    for (int i = gtid; i < ROWS*512; i += gs) {
        int r = i >> 9, cc = i & 511;
        float s = part[i] + part[PS+i] + part[2*PS+i] + part[3*PS+i] + bias[cc];
        feats[(size_t)r*NMID + 5 + cc] = s;
        feats_bf[(size_t)r*KP + 5 + cc] = f2bf(s);
    }
    for (int i = gtid; i < ROWS*5; i += gs) {
        int r = i / 5, cc = i - r*5;
        feats_bf[(size_t)r*KP + cc] = f2bf(feats[(size_t)r*NMID + cc]);
    }
    for (int i = gtid; i < ROWS*27; i += gs) {
        int r = i / 27, cc = i - r*27;
        feats_bf[(size_t)r*KP + 517 + cc] = 0;
    }
}

// ---------------------------------------------------------------------------
// bf16 MFMA GEMM (hxy only): tile 128x64, wave tile 64x32.
// ---------------------------------------------------------------------------
__global__ __launch_bounds__(256) void gemm_mfma(
    const unsigned short* __restrict__ A, const unsigned short* __restrict__ B,
    const float* __restrict__ bias, void* __restrict__ Cp,
    int K, int lda, int ldb, int ldc, int obf)
{
    __shared__ __align__(16) char As[8192];
    __shared__ __align__(16) char Bs[4096];
    int m0 = blockIdx.y * 128, n0 = blockIdx.x * 64;
    int tid = threadIdx.x;
    int lane = tid & 63, wave = tid >> 6;
    int wm = wave >> 1, wn = wave & 1;
    f32x4 acc[4][2];
    #pragma unroll
    for (int i = 0; i < 4; ++i)
        #pragma unroll
        for (int j = 0; j < 2; ++j) acc[i][j] = (f32x4){0.f,0.f,0.f,0.f};

    for (int k0 = 0; k0 < K; k0 += 32) {
        #pragma unroll
        for (int cc = tid; cc < 512; cc += 256) {
            int r = cc >> 2, q = cc & 3;
            uint4 v = *(const uint4*)(A + (size_t)(m0+r)*lda + k0 + q*8);
            *(uint4*)(As + ((r>>4)<<10) + (q<<8) + ((r&15)<<4)) = v;
        }
        {
            int r = tid >> 2, q = tid & 3;
            uint4 v = *(const uint4*)(B + (size_t)(n0+r)*ldb + k0 + q*8);
            *(uint4*)(Bs + ((r>>4)<<10) + (q<<8) + ((r&15)<<4)) = v;
        }
        __syncthreads();
        bf16x8 af[4], bfr[2];
        #pragma unroll
        for (int i = 0; i < 4; ++i) af[i]  = *(bf16x8*)(As + ((wm*4+i)<<10) + (lane<<4));
        #pragma unroll
        for (int j = 0; j < 2; ++j) bfr[j] = *(bf16x8*)(Bs + ((wn*2+j)<<10) + (lane<<4));
        #pragma unroll
        for (int i = 0; i < 4; ++i)
            #pragma unroll
            for (int j = 0; j < 2; ++j)
                acc[i][j] = __builtin_amdgcn_mfma_f32_16x16x32_bf16(af[i], bfr[j], acc[i][j], 0, 0, 0);
        __syncthreads();
    }
    int colf = lane & 15, rowq = lane >> 4;
    #pragma unroll
    for (int j = 0; j < 2; ++j) {
        int col = n0 + (wn*2+j)*16 + colf;
        float bv = bias ? bias[col] : 0.f;
        #pragma unroll
        for (int i = 0; i < 4; ++i) {
            #pragma unroll
            for (int reg = 0; reg < 4; ++reg) {
                int row = m0 + (wm*4+i)*16 + rowq*4 + reg;
                float v = acc[i][j][reg] + bv;
                if (obf) ((unsigned short*)Cp)[(size_t)row*ldc + col] = f2bf(v);
                else     ((float*)Cp)[(size_t)row*ldc + col] = v;
            }
        }
    }
}

// ---------------------------------------------------------------------------
// out_k: grid (128,4). rows i0..i0+8 of out[b][i][j] = w2.relu(hx_i+hy_j)
// ---------------------------------------------------------------------------
__global__ __launch_bounds__(256) void out_k(
    const float* __restrict__ hxy, const float* __restrict__ w2,
    float* __restrict__ out_g)
{
    __shared__ float s_hx[9*129], s_hy[NN*129], s_w2[NHID];
    int b = blockIdx.x, i0 = blockIdx.y * 9, tid = threadIdx.x;
    for (int i = tid; i < 9*NHID; i += 256) {
        int n = i >> 7, h = i & 127;
        s_hx[n*129+h] = hxy[(size_t)(b*NN+i0+n)*256 + h];
    }
    for (int i = tid; i < NN*NHID; i += 256) {
        int n = i >> 7, h = i & 127;
        s_hy[n*129+h] = hxy[(size_t)(b*NN+n)*256 + 128 + h];
    }
    if (tid < NHID) s_w2[tid] = w2[tid];
    __syncthreads();
    for (int idx = tid; idx < 9*NN; idx += 256) {
        int il = idx / NN, j = idx - il*NN;
        const float* px = &s_hx[il*129];
        const float* py = &s_hy[j*129];
        float s = 0.f;
        #pragma unroll 8
        for (int h = 0; h < NHID; ++h) s += s_w2[h] * fmaxf(px[h] + py[h], 0.f);
        out_g[(size_t)b*NN*NN + (i0+il)*NN + j] = s;
    }
}

// ---------------------------------------------------------------------------
// iter_k: grid 128. C = out - out^T, 3 assignment iters, final A row-softmax
// pre-scaled by sigmoid(att) -> A_g.
// ---------------------------------------------------------------------------
__global__ __launch_bounds__(256) void iter_k(
    const float* __restrict__ out_g, const float* __restrict__ att,
    const float* __restrict__ lr, float* __restrict__ A_g)
{
    __shared__ __align__(16) float s_out[NN*S40], s_C[NN*S40], s_logits[NN*S40], s_P[NN*S40];
    __shared__ float s_sg[NN];
    int b = blockIdx.x, tid = threadIdx.x;
    for (int idx = tid; idx < NN*NN; idx += 256) {
        int i = idx / NN, j = idx - i*NN;
        s_out[i*S40+j] = out_g[(size_t)b*NN*NN + idx];
        s_logits[i*S40+j] = 0.f;
    }
    if (tid < NN) s_sg[tid] = sigf(att[b*NN + tid]);
    float lr_abs = fabsf(lr[0]);
    __syncthreads();
    for (int idx = tid; idx < NN*NN; idx += 256) {
        int i = idx / NN, j = idx - i*NN;
        s_C[i*S40+j] = s_out[i*S40+j] - s_out[j*S40+i];
    }
    __syncthreads();
    for (int it = 0; it < 3; ++it) {
        if (tid < NN) {
            int i = tid;
            float mx = -1e30f;
            for (int l = 0; l < NN; ++l) mx = fmaxf(mx, s_logits[i*S40+l]);
            float sum = 0.f;
            for (int l = 0; l < NN; ++l) { float e = expf(s_logits[i*S40+l]-mx); s_P[i*S40+l] = e; sum += e; }
            float inv = 1.f/sum;
            for (int l = 0; l < NN; ++l) s_P[i*S40+l] *= inv;
        }
        __syncthreads();
        if (tid < NN) {
            int l = tid;
            float S = 0.f;
            for (int i = 0; i < NN; ++i) S += s_P[i*S40+l];
            float cum = 0.f;
            for (int i = 0; i < NN; ++i) {
                float p = s_P[i*S40+l];
                cum += p;
                s_P[i*S40+l] = S - 2.f*cum + p;
            }
        }
        __syncthreads();
        for (int idx = tid; idx < NN*NN; idx += 256) {
            int i = idx / NN, j = idx - i*NN;
            const f32x4* Pp = (const f32x4*)&s_P[i*S40];
            const f32x4* Cc = (const f32x4*)&s_C[j*S40];
            float g = 0.f;
            #pragma unroll
            for (int q = 0; q < 9; ++q) {
                f32x4 a = Pp[q], bb = Cc[q];
                g += a[0]*bb[0] + a[1]*bb[1] + a[2]*bb[2] + a[3]*bb[3];
            }
            s_logits[i*S40+j] -= lr_abs * g;
        }
        __syncthreads();
    }
    if (tid < NN) {
        int i = tid;
        float mx = -1e30f;
        for (int l = 0; l < NN; ++l) mx = fmaxf(mx, s_logits[i*S40+l]);
        float sum = 0.f;
        for (int l = 0; l < NN; ++l) { float e = expf(s_logits[i*S40+l]-mx); s_P[i*S40+l] = e; sum += e; }
        float inv = 1.f/sum;
        for (int l = 0; l < NN; ++l)
            A_g[(size_t)b*NN*NN + i*NN + l] = s_P[i*S40+l] * inv * s_sg[l];
    }
}

// ---------------------------------------------------------------------------
// xseq_k: grid (128,2). xseq[i][b][c] = sum_l A[b][i][l]*feats[b][l][c], bf16.
// ---------------------------------------------------------------------------
__global__ __launch_bounds__(256) void xseq_k(
    const float* __restrict__ feats, const float* __restrict__ A_g,
    unsigned short* __restrict__ xseq)
{
    __shared__ float s_P[NN*S37];
    int b = blockIdx.x, half = blockIdx.y, tid = threadIdx.x;
    for (int idx = tid; idx < NN*NN; idx += 256) {
        int i = idx / NN, l = idx - i*NN;
        s_P[i*S37+l] = A_g[(size_t)b*NN*NN + idx];
    }
    __syncthreads();
    const float* fb = feats + (size_t)b*NN*NMID;
    int ncols = (half == 0 && tid < 32) ? 2 : 1;
    #pragma unroll
    for (int rep = 0; rep < 2; ++rep) {
        if (rep >= ncols) break;
        int c = (rep == 0) ? half*256 + tid : 512 + tid;
        float colv[NN];
        #pragma unroll
        for (int l = 0; l < NN; ++l) colv[l] = (c < NMID) ? fb[l*NMID + c] : 0.f;
        #pragma unroll 4
        for (int i = 0; i < NN; ++i) {
            float s = 0.f;
            #pragma unroll
            for (int l = 0; l < NN; ++l) s += s_P[i*S37+l] * colv[l];
            xseq[((size_t)i*NB + b)*KP + c] = f2bf(s);
        }
    }
}

// ---------------------------------------------------------------------------
// LSTM step v7: grid 512 = bt(4 x 32batch) * 128 + ct(128 x 32col).
// Same-ct blocks land on the SAME XCD (stride 128 ≡ 0 mod 8) -> whh slice
// L2-resident. 64KB whh slice staged COALESCED (wave reads 1KB contiguous
// per row) into XOR-swizzled LDS (n' = n^(kc&15): stores and reads both
// 2-way = free). 69KB LDS -> 2 blocks/CU, 8 waves/CU.
// Wave tile 16b x 16c, A (=h) frags direct from global (L2-hot).
// ---------------------------------------------------------------------------
__global__ __launch_bounds__(256, 2) void lstm_step(
    const unsigned short* __restrict__ h_in, const unsigned short* __restrict__ whh,
    const unsigned short* __restrict__ xw_t, float* __restrict__ c,
    unsigned short* __restrict__ h_out, float* __restrict__ cout)
{
    __shared__ __align__(16) char Bls[65536];    // [kc 0..127][n' 0..31][16B]
    __shared__ __align__(16) float gates[32][36];
    int tid = threadIdx.x, lane = tid & 63, wave = tid >> 6;
    int bt = blockIdx.x >> 7, ct = blockIdx.x & 127;
    int m0 = bt * 32, n0 = ct * 32;
    // stage whh slice: 16 passes; each wave reads 1KB contiguous of one row
    #pragma unroll
    for (int r = 0; r < 16; ++r) {
        int idx = r*256 + tid;
        int n = idx >> 7, kc = idx & 127;
        uint4 v = *(const uint4*)(whh + (size_t)(n0+n)*NOUT + kc*8);
        *(uint4*)(Bls + kc*512 + (((n&16) | ((n^kc)&15))<<4)) = v;
    }
    __syncthreads();
    int wm = wave >> 1, wn = wave & 1;
    int q = lane >> 4, ml = lane & 15;
    const unsigned short* hrow = h_in + (size_t)(m0 + wm*16 + ml)*NOUT + q*8;
    int nl = wn*16 + ml;
    f32x4 acc = (f32x4){0.f,0.f,0.f,0.f};
    #pragma unroll 8
    for (int it = 0; it < 32; ++it) {
        int kc = it*4 + q;
        bf16x8 a = *(const bf16x8*)(hrow + it*32);
        bf16x8 b = *(const bf16x8*)(Bls + kc*512 + (((nl&16) | ((nl^kc)&15))<<4));
        acc = __builtin_amdgcn_mfma_f32_16x16x32_bf16(a, b, acc, 0, 0, 0);
    }
    #pragma unroll
    for (int reg = 0; reg < 4; ++reg)
        gates[wm*16 + q*4 + reg][wn*16 + ml] = acc[reg];
    __syncthreads();
    // epilogue: 32 batches x 8 units = 256 pairs, 1/thread
    {
        int ul = tid & 7, bl = tid >> 3;
        int b = m0 + bl, u = ct*8 + ul;
        float4 gl = *(const float4*)&gates[bl][ul*4];
        uint2 xw2 = *(const uint2*)(xw_t + (size_t)b*4*NOUT + n0 + ul*4);
        float g0 = gl.x + bf2f((unsigned short)(xw2.x & 0xffffu));
        float g1 = gl.y + bf2f((unsigned short)(xw2.x >> 16));
        float g2 = gl.z + bf2f((unsigned short)(xw2.y & 0xffffu));
        float g3 = gl.w + bf2f((unsigned short)(xw2.y >> 16));
        float ig = sigf(g0), fg = sigf(g1), gg = tanhf(g2), og = sigf(g3);
        size_t o = (size_t)b*NOUT + u;
        float cc = fg*c[o] + ig*gg;
        c[o] = cc;
        if (cout) cout[o] = cc;
        else      h_out[o] = f2bf(og*tanhf(cc));
    }
}

// ---------------------------------------------------------------------------
extern "C" void kernel_launch(void* const* d_in, const int* in_sizes, int n_in,
                              void* d_out, int out_size, void* d_ws, size_t ws_size,
                              hipStream_t stream) {
    (void)in_sizes; (void)n_in; (void)out_size; (void)ws_size;
    const float* boxes     = (const float*)d_in[0];
    const float* attention = (const float*)d_in[1];
    const float* features  = (const float*)d_in[2];
    const float* conv_w    = (const float*)d_in[3];
    const float* conv_b    = (const float*)d_in[4];
    const float* skew_wx   = (const float*)d_in[5];
    const float* skew_wy   = (const float*)d_in[6];
    const float* skew_b1   = (const float*)d_in[7];
    const float* skew_w2   = (const float*)d_in[8];
    // d_in[9] = skew_b2: cancels in C = out - out^T
    const float* w_ih      = (const float*)d_in[10];
    const float* w_hh      = (const float*)d_in[11];
    const float* b_ih      = (const float*)d_in[12];
    const float* b_hh      = (const float*)d_in[13];
    const float* lr        = (const float*)d_in[14];

    // workspace layout (bytes, 256-aligned). part (conv split-K partials)
    // and xw_bf share region 0 — partials dead before the xw GEMM writes.
    char* ws = (char*)d_ws;
    float*          part     = (float*)(ws);                      // 4x4608x512 f32  37,748,736
    unsigned short* xw_bf    = (unsigned short*)(ws);             // 4608x4096 bf16 (same region)
    unsigned short* features_bf = (unsigned short*)(ws + 37748736); // 18,874,368
    unsigned short* convw_bf = (unsigned short*)(ws + 56623104);  //  2,097,152
    float*          feats    = (float*)(ws + 58720256);           //  9,529,344
    float*          hxy      = (float*)(ws + 68249600);           //  4,718,592
    unsigned short* feats_bf = (unsigned short*)(ws + 72968192);  //  5,013,504
    unsigned short* xseq_bf  = (unsigned short*)(ws + 77981696);  //  5,013,504
    unsigned short* wih_il   = (unsigned short*)(ws + 82995200);  //  4,456,448
    unsigned short* whh_il   = (unsigned short*)(ws + 87451648);  //  8,388,608
    unsigned short* wxy_bf   = (unsigned short*)(ws + 95840256);  //    278,528
    float*          comb_b   = (float*)(ws + 96118784);           //     16,384
    float*          hxy_b    = (float*)(ws + 96135168);           //      1,024
    unsigned short* h0       = (unsigned short*)(ws + 96136192);  //    262,144
    unsigned short* h1       = (unsigned short*)(ws + 96398336);  //    262,144
    float*          out_g    = (float*)(ws + 96660480);           //    663,552
    float*          A_g      = (float*)(ws + 97324032);           //    663,552
    float*          cst      = (float*)(ws + 97987584);           //    524,288

    prep_all<<<2048, 256, 0, stream>>>(boxes, attention, features, conv_w,
                                       skew_wx, skew_wy, skew_b1, w_ih, w_hh,
                                       b_ih, b_hh, features_bf, convw_bf,
                                       wxy_bf, hxy_b, wih_il, whh_il, comb_b,
                                       h0, cst, feats);
    // conv split-K: 128x128 tiles, K-slice 512, grid (4,36,4) = 576 blocks
    gemm128<<<dim3(4, 36, 4), 256, 0, stream>>>(features_bf, convw_bf, nullptr,
                                                (void*)part, 512, NFEAT, NFEAT, 512, 0,
                                                (long long)ROWS*512);
    conv_reduce<<<2048, 256, 0, stream>>>(part, conv_b, feats, feats_bf);
    // hxy = feats . [wx;wy]^T + [b1;0]
    gemm_mfma<<<dim3(4, 36), 256, 0, stream>>>(feats_bf, wxy_bf, hxy_b,
                                               (void*)hxy, KP, KP, KP, 256, 0);
    // assignment pipeline
    out_k<<<dim3(NB, 4), 256, 0, stream>>>(hxy, skew_w2, out_g);
    iter_k<<<NB, 256, 0, stream>>>(out_g, attention, lr, A_g);
    xseq_k<<<dim3(NB, 2), 256, 0, stream>>>(feats, A_g, xseq_bf);
    // xw = xseq . w_ih_il^T + (b_ih+b_hh) -> bf16, 128x128 tiles, 1152 blocks
    gemm128<<<dim3(32, 36, 1), 256, 0, stream>>>(xseq_bf, wih_il, comb_b,
                                                 (void*)xw_bf, KP, KP, KP, 4*NOUT, 1, 0);
    unsigned short* hbuf[2] = {h0, h1};
    for (int t = 0; t < NN; ++t) {
        float* co = (t == NN-1) ? (float*)d_out : nullptr;
        lstm_step<<<512, 256, 0, stream>>>(hbuf[t & 1], whh_il,
                                           xw_bf + (size_t)t*NB*4*NOUT, cst,
                                           hbuf[(t+1) & 1], co);
    }
}